// Round 1
// baseline (129.331 us; speedup 1.0000x reference)
//
#include <hip/hip_runtime.h>
#include <hip/hip_bf16.h>

#define CIN  64
#define HH   128
#define WW   128
#define COUT 128
#define HO   126
#define WO   126
#define NB   32

typedef __bf16 bf16x8 __attribute__((ext_vector_type(8)));
typedef float f32x4 __attribute__((ext_vector_type(4)));

__device__ __forceinline__ unsigned short f2bf(float f) {
    unsigned int u = __builtin_bit_cast(unsigned int, f);
    u += 0x7fffu + ((u >> 16) & 1u);
    return (unsigned short)(u >> 16);
}

// reorder weight [128][64][3][3] f32 -> ws [9][128][64] bf16
__global__ void wreorder_3556(const float* __restrict__ w, unsigned short* __restrict__ ws) {
    int idx = blockIdx.x * 256 + threadIdx.x;
    if (idx >= 9 * 128 * 64) return;
    int s = idx >> 13;            // / 8192
    int r = idx & 8191;
    int cout = r >> 6, ci = r & 63;
    ws[idx] = f2bf(w[cout * 576 + ci * 9 + s]);
}

// LDS layout
#define XS_BYTES  (3 * 130 * 128)        // xs[row][col<130][ci64] bf16, 128B per (row,col)
#define WS_ROW    144                    // 72 bf16 per cout row (padded from 64)
#define WSL_BYTES (128 * WS_ROW)
#define PMIN_OFF  (XS_BYTES + WSL_BYTES)
#define SMEM_BYTES (PMIN_OFF + 2 * 128 * 4)

template<bool USE_WS>
__global__ __launch_bounds__(256, 2)
void conv_min_tanh_3556(const float* __restrict__ x, const float* __restrict__ w,
                        const float* __restrict__ bias,
                        const unsigned short* __restrict__ wsr,
                        float* __restrict__ out) {
    __shared__ __align__(16) unsigned char smem[SMEM_BYTES];
    unsigned char* xs  = smem;
    unsigned char* wsl = smem + XS_BYTES;
    float* pmin = (float*)(smem + PMIN_OFF);

    const int tid = threadIdx.x;
    const int blk = blockIdx.x;
    const int b  = blk / HO;
    const int ho = blk - b * HO;

    // ---- stage x tile: xs[row(3)][col(128 written of 130)][ci(64)] bf16, ci-granule XOR-swizzled by col&7
    {
        const float* xb = x + (size_t)b * (CIN * HH * WW);
        #pragma unroll
        for (int it = 0; it < 12; ++it) {
            int item = it * 256 + tid;          // 0..3071
            int col  = item & 127;
            int cig  = (item >> 7) & 7;         // group of 8 ci
            int row  = item >> 10;              // 0..2
            const float* src = xb + (size_t)(cig * 8) * (HH * WW) + (size_t)(ho + row) * WW + col;
            float v0 = src[0 * HH * WW], v1 = src[1 * HH * WW];
            float v2 = src[2 * HH * WW], v3 = src[3 * HH * WW];
            float v4 = src[4 * HH * WW], v5 = src[5 * HH * WW];
            float v6 = src[6 * HH * WW], v7 = src[7 * HH * WW];
            union { unsigned short us[8]; int4 i4; } p;
            p.us[0] = f2bf(v0); p.us[1] = f2bf(v1); p.us[2] = f2bf(v2); p.us[3] = f2bf(v3);
            p.us[4] = f2bf(v4); p.us[5] = f2bf(v5); p.us[6] = f2bf(v6); p.us[7] = f2bf(v7);
            int addr = (row * 130 + col) * 128 + ((cig ^ (col & 7)) << 4);
            *(int4*)(xs + addr) = p.i4;
        }
    }

    const int lane  = tid & 63;
    const int wid   = tid >> 6;
    const int waveM = wid >> 1, waveN = wid & 1;
    const int lr = lane & 15, lg = lane >> 4;

    f32x4 acc[4][4] = {};

    for (int s = 0; s < 9; ++s) {
        const int kh = s / 3, kw = s - kh * 3;
        __syncthreads();   // prev slice consumed (and xs staged, s==0)
        // ---- stage weight slice s into wsl[cout][72pad] bf16
        if (USE_WS) {
            const unsigned short* src = wsr + s * 8192;
            #pragma unroll
            for (int it = 0; it < 4; ++it) {
                int e = (it * 256 + tid) * 8;   // element index, mult of 8
                int cout = e >> 6, ci = e & 63;
                int4 v = *(const int4*)(src + e);
                *(int4*)(wsl + cout * WS_ROW + ci * 2) = v;
            }
        } else {
            #pragma unroll 4
            for (int it = 0; it < 32; ++it) {
                int idx = it * 256 + tid;
                int cout = idx >> 6, ci = idx & 63;
                unsigned short h = f2bf(w[cout * 576 + ci * 9 + s]);
                *(unsigned short*)(wsl + cout * WS_ROW + ci * 2) = h;
            }
        }
        __syncthreads();

        // ---- fragments
        bf16x8 af[4][2], bfr[4][2];
        #pragma unroll
        for (int m = 0; m < 4; ++m)
            #pragma unroll
            for (int kk = 0; kk < 2; ++kk) {
                int row = waveM * 64 + m * 16 + lr;
                int cib = kk * 32 + lg * 8;
                af[m][kk] = *(const bf16x8*)(wsl + row * WS_ROW + cib * 2);
            }
        #pragma unroll
        for (int n = 0; n < 4; ++n)
            #pragma unroll
            for (int kk = 0; kk < 2; ++kk) {
                int col = waveN * 64 + n * 16 + lr + kw;     // <=129
                int g = kk * 4 + lg;                          // 16B granule of ci
                int addr = (kh * 130 + col) * 128 + ((g ^ (col & 7)) << 4);
                bfr[n][kk] = *(const bf16x8*)(xs + addr);
            }
        #pragma unroll
        for (int kk = 0; kk < 2; ++kk)
            #pragma unroll
            for (int m = 0; m < 4; ++m)
                #pragma unroll
                for (int n = 0; n < 4; ++n)
                    acc[m][n] = __builtin_amdgcn_mfma_f32_16x16x32_bf16(
                        af[m][kk], bfr[n][kk], acc[m][n], 0, 0, 0);
    }

    // ---- epilogue: +bias, min over cout, tanh(tanh), store
    float pm[4] = {1e30f, 1e30f, 1e30f, 1e30f};
    #pragma unroll
    for (int m = 0; m < 4; ++m) {
        #pragma unroll
        for (int r = 0; r < 4; ++r) {
            int cout = waveM * 64 + m * 16 + lg * 4 + r;   // D row mapping
            float bv = bias[cout];
            #pragma unroll
            for (int n = 0; n < 4; ++n)
                pm[n] = fminf(pm[n], acc[m][n][r] + bv);
        }
    }
    #pragma unroll
    for (int n = 0; n < 4; ++n) {
        pm[n] = fminf(pm[n], __shfl_xor(pm[n], 16, 64));
        pm[n] = fminf(pm[n], __shfl_xor(pm[n], 32, 64));
    }
    if (lg == 0) {
        #pragma unroll
        for (int n = 0; n < 4; ++n) {
            int px = waveN * 64 + n * 16 + lr;            // D col mapping
            pmin[waveM * 128 + px] = pm[n];
        }
    }
    __syncthreads();
    if (tid < WO) {
        float v = fminf(pmin[tid], pmin[128 + tid]);
        v = tanhf(tanhf(v));
        out[((size_t)b * HO + ho) * WO + tid] = v;
    }
}

extern "C" void kernel_launch(void* const* d_in, const int* in_sizes, int n_in,
                              void* d_out, int out_size, void* d_ws, size_t ws_size,
                              hipStream_t stream) {
    const float* x    = (const float*)d_in[0];
    const float* w    = (const float*)d_in[1];
    const float* bias = (const float*)d_in[2];
    float* out = (float*)d_out;

    const size_t ws_needed = (size_t)9 * 128 * 64 * 2;   // 147456 B
    if (ws_size >= ws_needed) {
        unsigned short* wsb = (unsigned short*)d_ws;
        wreorder_3556<<<288, 256, 0, stream>>>(w, wsb);
        conv_min_tanh_3556<true><<<NB * HO, 256, 0, stream>>>(x, w, bias, wsb, out);
    } else {
        conv_min_tanh_3556<false><<<NB * HO, 256, 0, stream>>>(x, w, bias, nullptr, out);
    }
}